// Round 15
// baseline (1332.897 us; speedup 1.0000x reference)
//
#include <hip/hip_runtime.h>
#include <math.h>

typedef __bf16 bf16x8 __attribute__((ext_vector_type(8)));
typedef __bf16 bf16x4 __attribute__((ext_vector_type(4)));
typedef short  s16x4  __attribute__((ext_vector_type(4)));
typedef float  f32x4  __attribute__((ext_vector_type(4)));

#define NTOK 147456
#define LTOK 9216
#define ALPHA 1.8612097182041991f
#define QSCALE 5.656854249492380196f
#define MFMA32(a,b,c) __builtin_amdgcn_mfma_f32_16x16x32_bf16((a),(b),(c),0,0,0)
#define SWB(row,kb) ((kb) ^ ((row)&7))

// K=16 bf16 MFMA (attention only)
__device__ __forceinline__ f32x4 MFMA16(bf16x4 a, bf16x4 b, f32x4 c) {
#if __has_builtin(__builtin_amdgcn_mfma_f32_16x16x16bf16_1k)
    return __builtin_amdgcn_mfma_f32_16x16x16bf16_1k(*(s16x4*)&a, *(s16x4*)&b, c, 0, 0, 0);
#else
    f32x4 d = c;
    asm volatile("s_nop 1\n\ts_nop 1\n\t"
                 "v_mfma_f32_16x16x16_bf16 %0, %1, %2, %0\n\t"
                 "s_nop 7\n\ts_nop 7"
                 : "+v"(d) : "v"(a), "v"(b));
    return d;
#endif
}

__device__ __forceinline__ float gelu_sig(float x) {
    const float e = __expf(-1.702f * x);
    return x * __builtin_amdgcn_rcpf(1.0f + e);
}

__device__ __forceinline__ void gll16(const void* g, void* l) {
    __builtin_amdgcn_global_load_lds(
        (const __attribute__((address_space(1))) void*)g,
        (__attribute__((address_space(3))) void*)l, 16, 0, 0);
}

// ---------------------------------------------------------------------------
// k0: weights -> bf16 transposed [out][k]; + masked-bias table
// ---------------------------------------------------------------------------
__global__ __launch_bounds__(256) void k0_prep(
    const float* __restrict__ qkv_w, const float* __restrict__ proj_w,
    const float* __restrict__ fc1_w, const float* __restrict__ fc2_w,
    const float* __restrict__ bias_table,
    __bf16* __restrict__ qkvT, __bf16* __restrict__ projT,
    __bf16* __restrict__ w1T, __bf16* __restrict__ w2T,
    float* __restrict__ bmask)
{
    const int id = blockIdx.x * 256 + threadIdx.x;
    if (id < 196608) {
        const int o = id >> 8, k = id & 255;
        qkvT[id] = (__bf16)qkv_w[k * 768 + o];
    } else if (id < 262144) {
        const int i = id - 196608, o = i >> 8, k = i & 255;
        projT[i] = (__bf16)proj_w[k * 256 + o];
    } else if (id < 524288) {
        const int i = id - 262144, o = i >> 8, k = i & 255;
        w1T[i] = (__bf16)fc1_w[k * 1024 + o];
    } else if (id < 786432) {
        const int i = id - 524288, o = i >> 10, k = i & 1023;
        w2T[i] = (__bf16)fc2_w[k * 256 + o];
    } else if (id < 860160) {
        const int e = id - 786432;
        const int m = e % 48;
        const int n = (e / 48) % 48;
        const int h = (e / 2304) % 8;
        const int ty = e / 18432;
        const int nn = n < 36 ? n : 35, mm = m < 36 ? m : 35;
        const int i1 = nn / 6, j1 = nn - i1 * 6;
        const int i2 = mm / 6, j2 = mm - i2 * 6;
        float v = bias_table[((i1 - i2 + 5) * 11 + (j1 - j2 + 5)) * 8 + h];
        const int hg1 = (ty & 2) ? (i1 < 3 ? 1 : 2) : 0;
        const int wg1 = (ty & 1) ? (j1 < 3 ? 1 : 2) : 0;
        const int hg2 = (ty & 2) ? (i2 < 3 ? 1 : 2) : 0;
        const int wg2 = (ty & 1) ? (j2 < 3 ? 1 : 2) : 0;
        if (hg1 * 3 + wg1 != hg2 * 3 + wg2) v -= 100.0f;
        if (m >= 36) v = -1e30f;
        bmask[e] = v;
    }
}

// ---------------------------------------------------------------------------
// k1f v3 (round-12 exact): fused QKV GEMM + LDS-free attention.
// ---------------------------------------------------------------------------
__global__ __launch_bounds__(512, 4) void k1f_qkv_attn(
    const float* __restrict__ x, const __bf16* __restrict__ qkvT,
    const float* __restrict__ qkv_b, const float* __restrict__ bmask,
    __bf16* __restrict__ attnout)
{
    __shared__ __attribute__((aligned(16))) __bf16 As[48][256];
    __shared__ int srcrow[48];

    const int t = threadIdx.x;
    const int wid = t >> 6, lane = t & 63;
    const int l15 = lane & 15, lg = lane >> 4;
    const int blk = blockIdx.x;
    const int win = blk & 255;
    const int wh = win >> 4, ww = win & 15;
    const int h = wid;

    if (t < 48) {
        int n = t; if (n > 35) n = 35;
        const int b = blk >> 8;
        const int gh = (wh * 6 + n / 6 + 3) % 96;
        const int gw = (ww * 6 + n % 6 + 3) % 96;
        srcrow[t] = b * LTOK + gh * 96 + gw;
    }
    __syncthreads();

    for (int o = t; o < 48 * 32; o += 512) {
        const int row = o >> 5, kb = o & 31;
        const float* src = x + (size_t)srcrow[row] * 256 + kb * 8;
        const float4 f0 = *(const float4*)src;
        const float4 f1 = *(const float4*)(src + 4);
        bf16x8 p;
        p[0] = (__bf16)f0.x; p[1] = (__bf16)f0.y; p[2] = (__bf16)f0.z; p[3] = (__bf16)f0.w;
        p[4] = (__bf16)f1.x; p[5] = (__bf16)f1.y; p[6] = (__bf16)f1.z; p[7] = (__bf16)f1.w;
        *(bf16x8*)&As[row][SWB(row, kb) * 8] = p;
    }
    __syncthreads();

    const f32x4 fzero = {0.f, 0.f, 0.f, 0.f};
    f32x4 accQ[2][3], accK[2][3], accV[2][3];
    #pragma unroll
    for (int c = 0; c < 2; ++c)
        #pragma unroll
        for (int r = 0; r < 3; ++r) { accQ[c][r] = fzero; accK[c][r] = fzero; accV[c][r] = fzero; }

    const __bf16* bbase = qkvT + (size_t)(h * 32 + l15) * 256 + lg * 8;

    for (int kc = 0; kc < 8; ++kc) {
        bf16x8 af[3];
        #pragma unroll
        for (int rt = 0; rt < 3; ++rt) {
            const int ar = rt * 16 + l15;
            af[rt] = *(const bf16x8*)&As[ar][SWB(ar, kc * 4 + lg) * 8];
        }
        #pragma unroll
        for (int ct = 0; ct < 2; ++ct) {
            const __bf16* bp = bbase + (size_t)ct * 16 * 256 + kc * 32;
            const bf16x8 bq = *(const bf16x8*)bp;
            const bf16x8 bk = *(const bf16x8*)(bp + 65536);
            const bf16x8 bv = *(const bf16x8*)(bp + 131072);
            #pragma unroll
            for (int rt = 0; rt < 3; ++rt) {
                accQ[ct][rt] = MFMA32(bq, af[rt], accQ[ct][rt]);
                accK[ct][rt] = MFMA32(bk, af[rt], accK[ct][rt]);
                accV[ct][rt] = MFMA32(af[rt], bv, accV[ct][rt]);
            }
        }
    }

    bf16x4 qf[3][2], kf[3][2];
    bf16x4 vf[2][3];
    #pragma unroll
    for (int dh = 0; dh < 2; ++dh) {
        #pragma unroll
        for (int q = 0; q < 4; ++q) {
            const float qb = qkv_b[h * 32 + dh * 16 + lg * 4 + q];
            const float kb = qkv_b[256 + h * 32 + dh * 16 + lg * 4 + q];
            #pragma unroll
            for (int rt = 0; rt < 3; ++rt) {
                qf[rt][dh][q] = (__bf16)((accQ[dh][rt][q] + qb) * QSCALE);
                kf[rt][dh][q] = (__bf16)(accK[dh][rt][q] + kb);
            }
        }
    }
    #pragma unroll
    for (int cd = 0; cd < 2; ++cd) {
        const float vb = qkv_b[512 + h * 32 + cd * 16 + l15];
        #pragma unroll
        for (int c3 = 0; c3 < 3; ++c3)
            #pragma unroll
            for (int q = 0; q < 4; ++q)
                vf[cd][c3][q] = (__bf16)(accV[cd][c3][q] + vb);
    }

    f32x4 s[3][3];
    #pragma unroll
    for (int qt = 0; qt < 3; ++qt)
        #pragma unroll
        for (int c3 = 0; c3 < 3; ++c3) {
            f32x4 acc = MFMA16(kf[c3][0], qf[qt][0], fzero);
            s[qt][c3] = MFMA16(kf[c3][1], qf[qt][1], acc);
        }

    const int ty = ((wh == 15) ? 2 : 0) + ((ww == 15) ? 1 : 0);
    const float* bmp = bmask + (size_t)(ty * 8 + h) * 2304;
    bf16x4 pa[3][3];
    #pragma unroll
    for (int qt = 0; qt < 3; ++qt) {
        const float* brow = bmp + (qt * 16 + l15) * 48 + lg * 4;
        const float4 b0 = *(const float4*)brow;
        const float4 b1 = *(const float4*)(brow + 16);
        const float4 b2 = *(const float4*)(brow + 32);
        float vals[3][4];
        #pragma unroll
        for (int q = 0; q < 4; ++q) {
            vals[0][q] = s[qt][0][q] + ((const float*)&b0)[q];
            vals[1][q] = s[qt][1][q] + ((const float*)&b1)[q];
            vals[2][q] = s[qt][2][q] + ((const float*)&b2)[q];
        }
        float mx = -1e30f;
        #pragma unroll
        for (int c3 = 0; c3 < 3; ++c3)
            #pragma unroll
            for (int q = 0; q < 4; ++q) mx = fmaxf(mx, vals[c3][q]);
        mx = fmaxf(mx, __shfl_xor(mx, 16));
        mx = fmaxf(mx, __shfl_xor(mx, 32));
        float sum = 0.f;
        #pragma unroll
        for (int c3 = 0; c3 < 3; ++c3)
            #pragma unroll
            for (int q = 0; q < 4; ++q) {
                const float e = __expf(vals[c3][q] - mx);
                vals[c3][q] = e;
                sum += e;
            }
        sum += __shfl_xor(sum, 16);
        sum += __shfl_xor(sum, 32);
        const float inv = 1.0f / sum;
        #pragma unroll
        for (int c3 = 0; c3 < 3; ++c3)
            #pragma unroll
            for (int q = 0; q < 4; ++q)
                pa[qt][c3][q] = (__bf16)(vals[c3][q] * inv);
    }

    const size_t rowbase = (size_t)blk * 36;
    #pragma unroll
    for (int qt = 0; qt < 3; ++qt)
        #pragma unroll
        for (int cd = 0; cd < 2; ++cd) {
            f32x4 o = MFMA16(pa[qt][0], vf[cd][0], fzero);
            o = MFMA16(pa[qt][1], vf[cd][1], o);
            o = MFMA16(pa[qt][2], vf[cd][2], o);
            #pragma unroll
            for (int q = 0; q < 4; ++q) {
                const int n = qt * 16 + lg * 4 + q;
                if (n < 36)
                    attnout[(rowbase + n) * 256 + h * 32 + cd * 16 + l15] = (__bf16)o[q];
            }
        }
}

// ---------------------------------------------------------------------------
// k2: MFMA proj + roll permute + residual + LN1 -> x1b (bf16). Unchanged.
// ---------------------------------------------------------------------------
__global__ __launch_bounds__(512) void k2_proj_ln(
    const __bf16* __restrict__ attnout, const __bf16* __restrict__ projT,
    const float* __restrict__ proj_b, const float* __restrict__ x,
    const float* __restrict__ n1w, const float* __restrict__ n1b,
    __bf16* __restrict__ x1b)
{
    __shared__ __attribute__((aligned(16))) __bf16 As[128][64];
    __shared__ __attribute__((aligned(16))) __bf16 Bs[256][64];
    __shared__ float ps[128][4], ps2[128][4];
    const int t = threadIdx.x;
    const int wid = t >> 6, lane = t & 63;
    const int l15 = lane & 15, lg = lane >> 4;
    const int mb = blockIdx.x;
    const int wm = wid >> 2, wn = wid & 3;

    const f32x4 fzero = {0.f, 0.f, 0.f, 0.f};
    f32x4 acc[4][4];
    #pragma unroll
    for (int i = 0; i < 4; ++i)
        #pragma unroll
        for (int j = 0; j < 4; ++j) acc[i][j] = fzero;

    for (int kc = 0; kc < 4; ++kc) {
        __syncthreads();
        #pragma unroll
        for (int i = 0; i < 2; ++i) {
            const int r0 = wid * 16 + i * 8;
            const int row = r0 + (lane >> 3), kbl = lane & 7;
            gll16(attnout + (size_t)(mb * 128 + row) * 256 + kc * 64 + ((kbl ^ (row & 7)) * 8),
                  &As[r0][0]);
        }
        #pragma unroll
        for (int i = 0; i < 4; ++i) {
            const int r0 = wid * 32 + i * 8;
            const int row = r0 + (lane >> 3), kbl = lane & 7;
            gll16(projT + (size_t)row * 256 + kc * 64 + ((kbl ^ (row & 7)) * 8),
                  &Bs[r0][0]);
        }
        __syncthreads();
        #pragma unroll
        for (int kk = 0; kk < 2; ++kk) {
            bf16x8 af[4], bfr[4];
            #pragma unroll
            for (int rt = 0; rt < 4; ++rt) {
                const int ar = wm * 64 + rt * 16 + l15;
                af[rt] = *(const bf16x8*)&As[ar][((kk * 4 + lg) ^ (ar & 7)) * 8];
            }
            #pragma unroll
            for (int ct = 0; ct < 4; ++ct) {
                const int br = wn * 64 + ct * 16 + l15;
                bfr[ct] = *(const bf16x8*)&Bs[br][((kk * 4 + lg) ^ (br & 7)) * 8];
            }
            #pragma unroll
            for (int rt = 0; rt < 4; ++rt)
                #pragma unroll
                for (int ct = 0; ct < 4; ++ct)
                    acc[rt][ct] = MFMA32(af[rt], bfr[ct], acc[rt][ct]);
        }
    }

    int dtok_[4][4];
    #pragma unroll
    for (int rt = 0; rt < 4; ++rt) {
        #pragma unroll
        for (int q = 0; q < 4; ++q) {
            const int rowl = wm * 64 + rt * 16 + lg * 4 + q;
            const int tok = mb * 128 + rowl;
            const int b = tok / LTOK, l = tok % LTOK;
            const int hh = l / 96, wwp = l % 96;
            const int dtok = b * LTOK + ((hh + 3) % 96) * 96 + ((wwp + 3) % 96);
            dtok_[rt][q] = dtok;
            float s = 0.f, s2 = 0.f;
            #pragma unroll
            for (int ct = 0; ct < 4; ++ct) {
                const int col = wn * 64 + ct * 16 + l15;
                const float v = acc[rt][ct][q] + proj_b[col] + ALPHA * x[(size_t)dtok * 256 + col];
                acc[rt][ct][q] = v;
                s += v; s2 += v * v;
            }
            s  += __shfl_xor(s, 1, 16);  s += __shfl_xor(s, 2, 16);
            s  += __shfl_xor(s, 4, 16);  s += __shfl_xor(s, 8, 16);
            s2 += __shfl_xor(s2, 1, 16); s2 += __shfl_xor(s2, 2, 16);
            s2 += __shfl_xor(s2, 4, 16); s2 += __shfl_xor(s2, 8, 16);
            if (l15 == 0) { ps[rowl][wn] = s; ps2[rowl][wn] = s2; }
        }
    }
    __syncthreads();
    #pragma unroll
    for (int rt = 0; rt < 4; ++rt) {
        #pragma unroll
        for (int q = 0; q < 4; ++q) {
            const int rowl = wm * 64 + rt * 16 + lg * 4 + q;
            const float S  = ps[rowl][0] + ps[rowl][1] + ps[rowl][2] + ps[rowl][3];
            const float S2 = ps2[rowl][0] + ps2[rowl][1] + ps2[rowl][2] + ps2[rowl][3];
            const float mu = S * (1.0f / 256.0f);
            const float var = S2 * (1.0f / 256.0f) - mu * mu;
            const float rstd = rsqrtf(var + 1e-5f);
            __bf16* op = x1b + (size_t)dtok_[rt][q] * 256;
            #pragma unroll
            for (int ct = 0; ct < 4; ++ct) {
                const int col = wn * 64 + ct * 16 + l15;
                op[col] = (__bf16)((acc[rt][ct][q] - mu) * rstd * n1w[col] + n1b[col]);
            }
        }
    }
}

// ---------------------------------------------------------------------------
// k3f v8: v6 compute, SINGLE-buffered weights -> 47 KB LDS -> 3 blocks/CU.
// Per chunk: {barrier; STAGE; vmcnt(0); barrier; fc1; GELU->hs; fc2}.
// Block 256 (4 waves x 32 rows), grid 1152.
// ---------------------------------------------------------------------------
__global__ __launch_bounds__(256, 3) void k3f_mlp(
    const __bf16* __restrict__ x1b, const __bf16* __restrict__ w1T,
    const float* __restrict__ fc1_b, const __bf16* __restrict__ w2T,
    const float* __restrict__ fc2_b, const float* __restrict__ n2w,
    const float* __restrict__ n2b, float* __restrict__ out)
{
    __shared__ __attribute__((aligned(16))) __bf16 w1c[32][256];     // 16 KB
    __shared__ __attribute__((aligned(16))) __bf16 w2c[256][32];     // 16 KB
    __shared__ __attribute__((aligned(16))) __bf16 hs[4][32][32];    // 8 KB
    __shared__ float fc1b_s[1024], fc2b_s[256], n2w_s[256], n2b_s[256]; // 7 KB

    const int t = threadIdx.x;
    const int wv = t >> 6, lane = t & 63;
    const int l15 = lane & 15, lg = lane >> 4;
    const int rowbase = blockIdx.x * 128 + wv * 32;

    for (int o = t; o < 1024; o += 256) fc1b_s[o] = fc1_b[o];
    if (t < 256) { fc2b_s[t] = fc2_b[t]; n2w_s[t] = n2w[t]; n2b_s[t] = n2b[t]; }

    bf16x8 af[2][8];
    #pragma unroll
    for (int tt = 0; tt < 2; ++tt)
        #pragma unroll
        for (int kk = 0; kk < 8; ++kk)
            af[tt][kk] = *(const bf16x8*)(x1b + (size_t)(rowbase + tt * 16 + l15) * 256 + kk * 32 + lg * 8);

    const f32x4 fzero = {0.f, 0.f, 0.f, 0.f};
    f32x4 acc2[2][16];
    #pragma unroll
    for (int i = 0; i < 2; ++i)
        #pragma unroll
        for (int j = 0; j < 16; ++j) acc2[i][j] = fzero;

    // stage chunk c (32 hid): 4+4 gll per wave (source pre-swizzled to reads)
    #define STAGE_W(c)                                                           \
    {                                                                            \
        _Pragma("unroll")                                                        \
        for (int i = 0; i < 4; ++i) {                                            \
            const int r0 = wv * 8 + i * 2;                                       \
            const int row = r0 + (lane >> 5);                                    \
            const int g = (lane & 31) ^ (row & 7);                               \
            gll16(w1T + (size_t)((c) * 32 + row) * 256 + g * 8, &w1c[r0][0]);    \
        }                                                                        \
        _Pragma("unroll")                                                        \
        for (int i = 0; i < 4; ++i) {                                            \
            const int r0 = wv * 64 + i * 16;                                     \
            const int row = r0 + (lane >> 2);                                    \
            const int g = (lane & 3) ^ ((row >> 1) & 3);                         \
            gll16(w2T + (size_t)row * 1024 + (c) * 32 + g * 8, &w2c[r0][0]);     \
        }                                                                        \
    }

    for (int ch = 0; ch < 32; ++ch) {
        __syncthreads();                 // all waves done reading prev chunk (iter0: bias staging ordered)
        STAGE_W(ch);
        asm volatile("s_waitcnt vmcnt(0)" ::: "memory");
        __builtin_amdgcn_sched_barrier(0);
        __builtin_amdgcn_s_barrier();    // weights visible to all waves
        __builtin_amdgcn_sched_barrier(0);

        // ---- fc1 swapped: D[m=hid][n=token]; 32 hid x 32 rows ----
        f32x4 acc1[2][2];
        #pragma unroll
        for (int i = 0; i < 2; ++i)
            #pragma unroll
            for (int j = 0; j < 2; ++j) acc1[i][j] = fzero;
        __builtin_amdgcn_s_setprio(1);
        #pragma unroll
        for (int kk = 0; kk < 8; ++kk) {
            #pragma unroll
            for (int ht = 0; ht < 2; ++ht) {
                const int hr = ht * 16 + l15;
                const bf16x8 aW = *(const bf16x8*)&w1c[hr][((kk * 4 + lg) ^ (hr & 7)) * 8];
                #pragma unroll
                for (int tt = 0; tt < 2; ++tt)
                    acc1[ht][tt] = MFMA32(aW, af[tt][kk], acc1[ht][tt]);
            }
        }
        __builtin_amdgcn_s_setprio(0);

        // ---- GELU + pack -> hs (wave-private, 8B writes) ----
        #pragma unroll
        for (int ht = 0; ht < 2; ++ht) {
            float bq[4];
            #pragma unroll
            for (int q = 0; q < 4; ++q)
                bq[q] = fc1b_s[ch * 32 + ht * 16 + lg * 4 + q];
            #pragma unroll
            for (int tt = 0; tt < 2; ++tt) {
                bf16x4 p;
                #pragma unroll
                for (int q = 0; q < 4; ++q)
                    p[q] = (__bf16)gelu_sig(acc1[ht][tt][q] + bq[q]);
                const int row = tt * 16 + l15;
                const int gW = ht * 2 + (lg >> 1);
                *(bf16x4*)&hs[wv][row][(gW ^ ((row >> 1) & 3)) * 8 + (lg & 1) * 4] = p;
            }
        }

        // ---- fc2: 32 rows x 256 couts, K=32 ----
        bf16x8 a2[2];
        #pragma unroll
        for (int tt = 0; tt < 2; ++tt) {
            const int row = tt * 16 + l15;
            a2[tt] = *(const bf16x8*)&hs[wv][row][((lg ^ ((row >> 1) & 3))) * 8];
        }
        __builtin_amdgcn_s_setprio(1);
        #pragma unroll
        for (int ct = 0; ct < 16; ++ct) {
            const int br = ct * 16 + l15;
            const bf16x8 bW = *(const bf16x8*)&w2c[br][((lg ^ ((br >> 1) & 3))) * 8];
            #pragma unroll
            for (int tt = 0; tt < 2; ++tt)
                acc2[tt][ct] = MFMA32(a2[tt], bW, acc2[tt][ct]);
        }
        __builtin_amdgcn_s_setprio(0);
    }

    // ---- epilogue: bias + residual + LN2, fully in-wave ----
    #pragma unroll
    for (int tt = 0; tt < 2; ++tt) {
        #pragma unroll
        for (int q = 0; q < 4; ++q) {
            const int grow = tt * 16 + lg * 4 + q;
            const size_t tok = (size_t)(rowbase + grow);
            float s = 0.f, s2 = 0.f;
            float vals[16];
            #pragma unroll
            for (int ct = 0; ct < 16; ++ct) {
                const int col = ct * 16 + l15;
                const float v = acc2[tt][ct][q] + fc2b_s[col] + ALPHA * (float)x1b[tok * 256 + col];
                vals[ct] = v;
                s += v; s2 += v * v;
            }
            s  += __shfl_xor(s, 1, 16);  s += __shfl_xor(s, 2, 16);
            s  += __shfl_xor(s, 4, 16);  s += __shfl_xor(s, 8, 16);
            s2 += __shfl_xor(s2, 1, 16); s2 += __shfl_xor(s2, 2, 16);
            s2 += __shfl_xor(s2, 4, 16); s2 += __shfl_xor(s2, 8, 16);
            const float mu = s * (1.0f / 256.0f);
            const float var = s2 * (1.0f / 256.0f) - mu * mu;
            const float rstd = rsqrtf(var + 1e-5f);
            float* op = out + tok * 256;
            #pragma unroll
            for (int ct = 0; ct < 16; ++ct) {
                const int col = ct * 16 + l15;
                op[col] = (vals[ct] - mu) * rstd * n2w_s[col] + n2b_s[col];
            }
        }
    }
    #undef STAGE_W
}

// ---------------------------------------------------------------------------
extern "C" void kernel_launch(void* const* d_in, const int* in_sizes, int n_in,
                              void* d_out, int out_size, void* d_ws, size_t ws_size,
                              hipStream_t stream)
{
    const float* x          = (const float*)d_in[0];
    const float* qkv_w      = (const float*)d_in[1];
    const float* qkv_b      = (const float*)d_in[2];
    const float* bias_table = (const float*)d_in[3];
    const float* proj_w     = (const float*)d_in[4];
    const float* proj_b     = (const float*)d_in[5];
    const float* n1w        = (const float*)d_in[6];
    const float* n1b        = (const float*)d_in[7];
    const float* n2w        = (const float*)d_in[8];
    const float* n2b        = (const float*)d_in[9];
    const float* fc1_w      = (const float*)d_in[10];
    const float* fc1_b      = (const float*)d_in[11];
    const float* fc2_w      = (const float*)d_in[12];
    const float* fc2_b      = (const float*)d_in[13];
    float* out = (float*)d_out;

    // ws layout (bytes):
    //   [0,          75497472)  x1b bf16
    //   [75497472,  150994944)  attnout bf16
    //   [150994944, 152567808)  weight tables
    //   [152567808, 152862720)  bmask fp32 [4][8][48][48]
    char* ws = (char*)d_ws;
    __bf16* x1b     = (__bf16*)ws;
    __bf16* attnout = (__bf16*)(ws + 75497472);
    __bf16* qkvT    = (__bf16*)(ws + 150994944);
    __bf16* projT   = (__bf16*)(ws + 151388160);
    __bf16* w1T     = (__bf16*)(ws + 151519232);
    __bf16* w2T     = (__bf16*)(ws + 152043520);
    float*  bmask   = (float*)(ws + 152567808);

    k0_prep<<<3360, 256, 0, stream>>>(qkv_w, proj_w, fc1_w, fc2_w, bias_table,
                                      qkvT, projT, w1T, w2T, bmask);
    k1f_qkv_attn<<<4096, 512, 0, stream>>>(x, qkvT, qkv_b, bmask, attnout);
    k2_proj_ln<<<1152, 512, 0, stream>>>(attnout, projT, proj_b, x, n1w, n1b, x1b);
    k3f_mlp<<<1152, 256, 0, stream>>>(x1b, w1T, fc1_b, w2T, fc2_b, n2w, n2b, out);
}

// Round 16
// 596.722 us; speedup vs baseline: 2.2337x; 2.2337x over previous
//
#include <hip/hip_runtime.h>
#include <math.h>

typedef __bf16 bf16x8 __attribute__((ext_vector_type(8)));
typedef __bf16 bf16x4 __attribute__((ext_vector_type(4)));
typedef short  s16x4  __attribute__((ext_vector_type(4)));
typedef float  f32x4  __attribute__((ext_vector_type(4)));

#define NTOK 147456
#define LTOK 9216
#define ALPHA 1.8612097182041991f
#define QSCALE 5.656854249492380196f
#define MFMA32(a,b,c) __builtin_amdgcn_mfma_f32_16x16x32_bf16((a),(b),(c),0,0,0)
#define SWB(row,kb) ((kb) ^ ((row)&7))

// K=16 bf16 MFMA (attention only)
__device__ __forceinline__ f32x4 MFMA16(bf16x4 a, bf16x4 b, f32x4 c) {
#if __has_builtin(__builtin_amdgcn_mfma_f32_16x16x16bf16_1k)
    return __builtin_amdgcn_mfma_f32_16x16x16bf16_1k(*(s16x4*)&a, *(s16x4*)&b, c, 0, 0, 0);
#else
    f32x4 d = c;
    asm volatile("s_nop 1\n\ts_nop 1\n\t"
                 "v_mfma_f32_16x16x16_bf16 %0, %1, %2, %0\n\t"
                 "s_nop 7\n\ts_nop 7"
                 : "+v"(d) : "v"(a), "v"(b));
    return d;
#endif
}

__device__ __forceinline__ float gelu_sig(float x) {
    const float e = __expf(-1.702f * x);
    return x * __builtin_amdgcn_rcpf(1.0f + e);
}

__device__ __forceinline__ void gll16(const void* g, void* l) {
    __builtin_amdgcn_global_load_lds(
        (const __attribute__((address_space(1))) void*)g,
        (__attribute__((address_space(3))) void*)l, 16, 0, 0);
}

// ---------------------------------------------------------------------------
// k0: weights -> bf16 transposed [out][k]; + masked-bias table
// ---------------------------------------------------------------------------
__global__ __launch_bounds__(256) void k0_prep(
    const float* __restrict__ qkv_w, const float* __restrict__ proj_w,
    const float* __restrict__ fc1_w, const float* __restrict__ fc2_w,
    const float* __restrict__ bias_table,
    __bf16* __restrict__ qkvT, __bf16* __restrict__ projT,
    __bf16* __restrict__ w1T, __bf16* __restrict__ w2T,
    float* __restrict__ bmask)
{
    const int id = blockIdx.x * 256 + threadIdx.x;
    if (id < 196608) {
        const int o = id >> 8, k = id & 255;
        qkvT[id] = (__bf16)qkv_w[k * 768 + o];
    } else if (id < 262144) {
        const int i = id - 196608, o = i >> 8, k = i & 255;
        projT[i] = (__bf16)proj_w[k * 256 + o];
    } else if (id < 524288) {
        const int i = id - 262144, o = i >> 8, k = i & 255;
        w1T[i] = (__bf16)fc1_w[k * 1024 + o];
    } else if (id < 786432) {
        const int i = id - 524288, o = i >> 10, k = i & 1023;
        w2T[i] = (__bf16)fc2_w[k * 256 + o];
    } else if (id < 860160) {
        const int e = id - 786432;
        const int m = e % 48;
        const int n = (e / 48) % 48;
        const int h = (e / 2304) % 8;
        const int ty = e / 18432;
        const int nn = n < 36 ? n : 35, mm = m < 36 ? m : 35;
        const int i1 = nn / 6, j1 = nn - i1 * 6;
        const int i2 = mm / 6, j2 = mm - i2 * 6;
        float v = bias_table[((i1 - i2 + 5) * 11 + (j1 - j2 + 5)) * 8 + h];
        const int hg1 = (ty & 2) ? (i1 < 3 ? 1 : 2) : 0;
        const int wg1 = (ty & 1) ? (j1 < 3 ? 1 : 2) : 0;
        const int hg2 = (ty & 2) ? (i2 < 3 ? 1 : 2) : 0;
        const int wg2 = (ty & 1) ? (j2 < 3 ? 1 : 2) : 0;
        if (hg1 * 3 + wg1 != hg2 * 3 + wg2) v -= 100.0f;
        if (m >= 36) v = -1e30f;
        bmask[e] = v;
    }
}

// ---------------------------------------------------------------------------
// k1f v3 (round-12 exact): fused QKV GEMM + LDS-free attention.
// ---------------------------------------------------------------------------
__global__ __launch_bounds__(512, 4) void k1f_qkv_attn(
    const float* __restrict__ x, const __bf16* __restrict__ qkvT,
    const float* __restrict__ qkv_b, const float* __restrict__ bmask,
    __bf16* __restrict__ attnout)
{
    __shared__ __attribute__((aligned(16))) __bf16 As[48][256];
    __shared__ int srcrow[48];

    const int t = threadIdx.x;
    const int wid = t >> 6, lane = t & 63;
    const int l15 = lane & 15, lg = lane >> 4;
    const int blk = blockIdx.x;
    const int win = blk & 255;
    const int wh = win >> 4, ww = win & 15;
    const int h = wid;

    if (t < 48) {
        int n = t; if (n > 35) n = 35;
        const int b = blk >> 8;
        const int gh = (wh * 6 + n / 6 + 3) % 96;
        const int gw = (ww * 6 + n % 6 + 3) % 96;
        srcrow[t] = b * LTOK + gh * 96 + gw;
    }
    __syncthreads();

    for (int o = t; o < 48 * 32; o += 512) {
        const int row = o >> 5, kb = o & 31;
        const float* src = x + (size_t)srcrow[row] * 256 + kb * 8;
        const float4 f0 = *(const float4*)src;
        const float4 f1 = *(const float4*)(src + 4);
        bf16x8 p;
        p[0] = (__bf16)f0.x; p[1] = (__bf16)f0.y; p[2] = (__bf16)f0.z; p[3] = (__bf16)f0.w;
        p[4] = (__bf16)f1.x; p[5] = (__bf16)f1.y; p[6] = (__bf16)f1.z; p[7] = (__bf16)f1.w;
        *(bf16x8*)&As[row][SWB(row, kb) * 8] = p;
    }
    __syncthreads();

    const f32x4 fzero = {0.f, 0.f, 0.f, 0.f};
    f32x4 accQ[2][3], accK[2][3], accV[2][3];
    #pragma unroll
    for (int c = 0; c < 2; ++c)
        #pragma unroll
        for (int r = 0; r < 3; ++r) { accQ[c][r] = fzero; accK[c][r] = fzero; accV[c][r] = fzero; }

    const __bf16* bbase = qkvT + (size_t)(h * 32 + l15) * 256 + lg * 8;

    for (int kc = 0; kc < 8; ++kc) {
        bf16x8 af[3];
        #pragma unroll
        for (int rt = 0; rt < 3; ++rt) {
            const int ar = rt * 16 + l15;
            af[rt] = *(const bf16x8*)&As[ar][SWB(ar, kc * 4 + lg) * 8];
        }
        #pragma unroll
        for (int ct = 0; ct < 2; ++ct) {
            const __bf16* bp = bbase + (size_t)ct * 16 * 256 + kc * 32;
            const bf16x8 bq = *(const bf16x8*)bp;
            const bf16x8 bk = *(const bf16x8*)(bp + 65536);
            const bf16x8 bv = *(const bf16x8*)(bp + 131072);
            #pragma unroll
            for (int rt = 0; rt < 3; ++rt) {
                accQ[ct][rt] = MFMA32(bq, af[rt], accQ[ct][rt]);
                accK[ct][rt] = MFMA32(bk, af[rt], accK[ct][rt]);
                accV[ct][rt] = MFMA32(af[rt], bv, accV[ct][rt]);
            }
        }
    }

    bf16x4 qf[3][2], kf[3][2];
    bf16x4 vf[2][3];
    #pragma unroll
    for (int dh = 0; dh < 2; ++dh) {
        #pragma unroll
        for (int q = 0; q < 4; ++q) {
            const float qb = qkv_b[h * 32 + dh * 16 + lg * 4 + q];
            const float kb = qkv_b[256 + h * 32 + dh * 16 + lg * 4 + q];
            #pragma unroll
            for (int rt = 0; rt < 3; ++rt) {
                qf[rt][dh][q] = (__bf16)((accQ[dh][rt][q] + qb) * QSCALE);
                kf[rt][dh][q] = (__bf16)(accK[dh][rt][q] + kb);
            }
        }
    }
    #pragma unroll
    for (int cd = 0; cd < 2; ++cd) {
        const float vb = qkv_b[512 + h * 32 + cd * 16 + l15];
        #pragma unroll
        for (int c3 = 0; c3 < 3; ++c3)
            #pragma unroll
            for (int q = 0; q < 4; ++q)
                vf[cd][c3][q] = (__bf16)(accV[cd][c3][q] + vb);
    }

    f32x4 s[3][3];
    #pragma unroll
    for (int qt = 0; qt < 3; ++qt)
        #pragma unroll
        for (int c3 = 0; c3 < 3; ++c3) {
            f32x4 acc = MFMA16(kf[c3][0], qf[qt][0], fzero);
            s[qt][c3] = MFMA16(kf[c3][1], qf[qt][1], acc);
        }

    const int ty = ((wh == 15) ? 2 : 0) + ((ww == 15) ? 1 : 0);
    const float* bmp = bmask + (size_t)(ty * 8 + h) * 2304;
    bf16x4 pa[3][3];
    #pragma unroll
    for (int qt = 0; qt < 3; ++qt) {
        const float* brow = bmp + (qt * 16 + l15) * 48 + lg * 4;
        const float4 b0 = *(const float4*)brow;
        const float4 b1 = *(const float4*)(brow + 16);
        const float4 b2 = *(const float4*)(brow + 32);
        float vals[3][4];
        #pragma unroll
        for (int q = 0; q < 4; ++q) {
            vals[0][q] = s[qt][0][q] + ((const float*)&b0)[q];
            vals[1][q] = s[qt][1][q] + ((const float*)&b1)[q];
            vals[2][q] = s[qt][2][q] + ((const float*)&b2)[q];
        }
        float mx = -1e30f;
        #pragma unroll
        for (int c3 = 0; c3 < 3; ++c3)
            #pragma unroll
            for (int q = 0; q < 4; ++q) mx = fmaxf(mx, vals[c3][q]);
        mx = fmaxf(mx, __shfl_xor(mx, 16));
        mx = fmaxf(mx, __shfl_xor(mx, 32));
        float sum = 0.f;
        #pragma unroll
        for (int c3 = 0; c3 < 3; ++c3)
            #pragma unroll
            for (int q = 0; q < 4; ++q) {
                const float e = __expf(vals[c3][q] - mx);
                vals[c3][q] = e;
                sum += e;
            }
        sum += __shfl_xor(sum, 16);
        sum += __shfl_xor(sum, 32);
        const float inv = 1.0f / sum;
        #pragma unroll
        for (int c3 = 0; c3 < 3; ++c3)
            #pragma unroll
            for (int q = 0; q < 4; ++q)
                pa[qt][c3][q] = (__bf16)(vals[c3][q] * inv);
    }

    const size_t rowbase = (size_t)blk * 36;
    #pragma unroll
    for (int qt = 0; qt < 3; ++qt)
        #pragma unroll
        for (int cd = 0; cd < 2; ++cd) {
            f32x4 o = MFMA16(pa[qt][0], vf[cd][0], fzero);
            o = MFMA16(pa[qt][1], vf[cd][1], o);
            o = MFMA16(pa[qt][2], vf[cd][2], o);
            #pragma unroll
            for (int q = 0; q < 4; ++q) {
                const int n = qt * 16 + lg * 4 + q;
                if (n < 36)
                    attnout[(rowbase + n) * 256 + h * 32 + cd * 16 + l15] = (__bf16)o[q];
            }
        }
}

// ---------------------------------------------------------------------------
// k2: MFMA proj + roll permute + residual + LN1 -> x1b (bf16). Unchanged.
// ---------------------------------------------------------------------------
__global__ __launch_bounds__(512) void k2_proj_ln(
    const __bf16* __restrict__ attnout, const __bf16* __restrict__ projT,
    const float* __restrict__ proj_b, const float* __restrict__ x,
    const float* __restrict__ n1w, const float* __restrict__ n1b,
    __bf16* __restrict__ x1b)
{
    __shared__ __attribute__((aligned(16))) __bf16 As[128][64];
    __shared__ __attribute__((aligned(16))) __bf16 Bs[256][64];
    __shared__ float ps[128][4], ps2[128][4];
    const int t = threadIdx.x;
    const int wid = t >> 6, lane = t & 63;
    const int l15 = lane & 15, lg = lane >> 4;
    const int mb = blockIdx.x;
    const int wm = wid >> 2, wn = wid & 3;

    const f32x4 fzero = {0.f, 0.f, 0.f, 0.f};
    f32x4 acc[4][4];
    #pragma unroll
    for (int i = 0; i < 4; ++i)
        #pragma unroll
        for (int j = 0; j < 4; ++j) acc[i][j] = fzero;

    for (int kc = 0; kc < 4; ++kc) {
        __syncthreads();
        #pragma unroll
        for (int i = 0; i < 2; ++i) {
            const int r0 = wid * 16 + i * 8;
            const int row = r0 + (lane >> 3), kbl = lane & 7;
            gll16(attnout + (size_t)(mb * 128 + row) * 256 + kc * 64 + ((kbl ^ (row & 7)) * 8),
                  &As[r0][0]);
        }
        #pragma unroll
        for (int i = 0; i < 4; ++i) {
            const int r0 = wid * 32 + i * 8;
            const int row = r0 + (lane >> 3), kbl = lane & 7;
            gll16(projT + (size_t)row * 256 + kc * 64 + ((kbl ^ (row & 7)) * 8),
                  &Bs[r0][0]);
        }
        __syncthreads();
        #pragma unroll
        for (int kk = 0; kk < 2; ++kk) {
            bf16x8 af[4], bfr[4];
            #pragma unroll
            for (int rt = 0; rt < 4; ++rt) {
                const int ar = wm * 64 + rt * 16 + l15;
                af[rt] = *(const bf16x8*)&As[ar][((kk * 4 + lg) ^ (ar & 7)) * 8];
            }
            #pragma unroll
            for (int ct = 0; ct < 4; ++ct) {
                const int br = wn * 64 + ct * 16 + l15;
                bfr[ct] = *(const bf16x8*)&Bs[br][((kk * 4 + lg) ^ (br & 7)) * 8];
            }
            #pragma unroll
            for (int rt = 0; rt < 4; ++rt)
                #pragma unroll
                for (int ct = 0; ct < 4; ++ct)
                    acc[rt][ct] = MFMA32(af[rt], bfr[ct], acc[rt][ct]);
        }
    }

    int dtok_[4][4];
    #pragma unroll
    for (int rt = 0; rt < 4; ++rt) {
        #pragma unroll
        for (int q = 0; q < 4; ++q) {
            const int rowl = wm * 64 + rt * 16 + lg * 4 + q;
            const int tok = mb * 128 + rowl;
            const int b = tok / LTOK, l = tok % LTOK;
            const int hh = l / 96, wwp = l % 96;
            const int dtok = b * LTOK + ((hh + 3) % 96) * 96 + ((wwp + 3) % 96);
            dtok_[rt][q] = dtok;
            float s = 0.f, s2 = 0.f;
            #pragma unroll
            for (int ct = 0; ct < 4; ++ct) {
                const int col = wn * 64 + ct * 16 + l15;
                const float v = acc[rt][ct][q] + proj_b[col] + ALPHA * x[(size_t)dtok * 256 + col];
                acc[rt][ct][q] = v;
                s += v; s2 += v * v;
            }
            s  += __shfl_xor(s, 1, 16);  s += __shfl_xor(s, 2, 16);
            s  += __shfl_xor(s, 4, 16);  s += __shfl_xor(s, 8, 16);
            s2 += __shfl_xor(s2, 1, 16); s2 += __shfl_xor(s2, 2, 16);
            s2 += __shfl_xor(s2, 4, 16); s2 += __shfl_xor(s2, 8, 16);
            if (l15 == 0) { ps[rowl][wn] = s; ps2[rowl][wn] = s2; }
        }
    }
    __syncthreads();
    #pragma unroll
    for (int rt = 0; rt < 4; ++rt) {
        #pragma unroll
        for (int q = 0; q < 4; ++q) {
            const int rowl = wm * 64 + rt * 16 + lg * 4 + q;
            const float S  = ps[rowl][0] + ps[rowl][1] + ps[rowl][2] + ps[rowl][3];
            const float S2 = ps2[rowl][0] + ps2[rowl][1] + ps2[rowl][2] + ps2[rowl][3];
            const float mu = S * (1.0f / 256.0f);
            const float var = S2 * (1.0f / 256.0f) - mu * mu;
            const float rstd = rsqrtf(var + 1e-5f);
            __bf16* op = x1b + (size_t)dtok_[rt][q] * 256;
            #pragma unroll
            for (int ct = 0; ct < 4; ++ct) {
                const int col = wn * 64 + ct * 16 + l15;
                op[col] = (__bf16)((acc[rt][ct][q] - mu) * rstd * n1w[col] + n1b[col]);
            }
        }
    }
}

// ---------------------------------------------------------------------------
// k3f v6 (round-12 exact): dbuf weights in LDS, (row>>1)&3 swizzle,
// biases in LDS, setprio. Block 256 (4 waves x 32 rows), grid 1152.
// NOTE: __launch_bounds__(256,2) is load-bearing — (256,3) caps VGPRs at 84
// and spills the 128-reg accumulator to scratch (round-15 regression).
// ---------------------------------------------------------------------------
__global__ __launch_bounds__(256, 2) void k3f_mlp(
    const __bf16* __restrict__ x1b, const __bf16* __restrict__ w1T,
    const float* __restrict__ fc1_b, const __bf16* __restrict__ w2T,
    const float* __restrict__ fc2_b, const float* __restrict__ n2w,
    const float* __restrict__ n2b, float* __restrict__ out)
{
    __shared__ __attribute__((aligned(16))) __bf16 w1c[2][32][256];  // 32 KB
    __shared__ __attribute__((aligned(16))) __bf16 w2c[2][256][32];  // 32 KB
    __shared__ __attribute__((aligned(16))) __bf16 hs[4][32][32];    // 8 KB
    __shared__ float fc1b_s[1024], fc2b_s[256], n2w_s[256], n2b_s[256]; // 7 KB

    const int t = threadIdx.x;
    const int wv = t >> 6, lane = t & 63;
    const int l15 = lane & 15, lg = lane >> 4;
    const int rowbase = blockIdx.x * 128 + wv * 32;

    for (int o = t; o < 1024; o += 256) fc1b_s[o] = fc1_b[o];
    if (t < 256) { fc2b_s[t] = fc2_b[t]; n2w_s[t] = n2w[t]; n2b_s[t] = n2b[t]; }

    bf16x8 af[2][8];
    #pragma unroll
    for (int tt = 0; tt < 2; ++tt)
        #pragma unroll
        for (int kk = 0; kk < 8; ++kk)
            af[tt][kk] = *(const bf16x8*)(x1b + (size_t)(rowbase + tt * 16 + l15) * 256 + kk * 32 + lg * 8);

    const f32x4 fzero = {0.f, 0.f, 0.f, 0.f};
    f32x4 acc2[2][16];
    #pragma unroll
    for (int i = 0; i < 2; ++i)
        #pragma unroll
        for (int j = 0; j < 16; ++j) acc2[i][j] = fzero;

    #define STAGE_W(b, c)                                                        \
    {                                                                            \
        _Pragma("unroll")                                                        \
        for (int i = 0; i < 4; ++i) {                                            \
            const int r0 = wv * 8 + i * 2;                                       \
            const int row = r0 + (lane >> 5);                                    \
            const int g = (lane & 31) ^ (row & 7);                               \
            gll16(w1T + (size_t)((c) * 32 + row) * 256 + g * 8, &w1c[b][r0][0]); \
        }                                                                        \
        _Pragma("unroll")                                                        \
        for (int i = 0; i < 4; ++i) {                                            \
            const int r0 = wv * 64 + i * 16;                                     \
            const int row = r0 + (lane >> 2);                                    \
            const int g = (lane & 3) ^ ((row >> 1) & 3);                         \
            gll16(w2T + (size_t)row * 1024 + (c) * 32 + g * 8, &w2c[b][r0][0]);  \
        }                                                                        \
    }

    STAGE_W(0, 0);
    asm volatile("s_waitcnt vmcnt(0)" ::: "memory");
    __builtin_amdgcn_sched_barrier(0);
    __builtin_amdgcn_s_barrier();
    __builtin_amdgcn_sched_barrier(0);

    for (int ch = 0; ch < 32; ++ch) {
        const int cur = ch & 1;
        if (ch < 31) STAGE_W(cur ^ 1, ch + 1);

        f32x4 acc1[2][2];
        #pragma unroll
        for (int i = 0; i < 2; ++i)
            #pragma unroll
            for (int j = 0; j < 2; ++j) acc1[i][j] = fzero;
        __builtin_amdgcn_s_setprio(1);
        #pragma unroll
        for (int kk = 0; kk < 8; ++kk) {
            #pragma unroll
            for (int ht = 0; ht < 2; ++ht) {
                const int hr = ht * 16 + l15;
                const bf16x8 aW = *(const bf16x8*)&w1c[cur][hr][((kk * 4 + lg) ^ (hr & 7)) * 8];
                #pragma unroll
                for (int tt = 0; tt < 2; ++tt)
                    acc1[ht][tt] = MFMA32(aW, af[tt][kk], acc1[ht][tt]);
            }
        }
        __builtin_amdgcn_s_setprio(0);

        #pragma unroll
        for (int ht = 0; ht < 2; ++ht) {
            float bq[4];
            #pragma unroll
            for (int q = 0; q < 4; ++q)
                bq[q] = fc1b_s[ch * 32 + ht * 16 + lg * 4 + q];
            #pragma unroll
            for (int tt = 0; tt < 2; ++tt) {
                bf16x4 p;
                #pragma unroll
                for (int q = 0; q < 4; ++q)
                    p[q] = (__bf16)gelu_sig(acc1[ht][tt][q] + bq[q]);
                const int row = tt * 16 + l15;
                const int gW = ht * 2 + (lg >> 1);
                *(bf16x4*)&hs[wv][row][(gW ^ ((row >> 1) & 3)) * 8 + (lg & 1) * 4] = p;
            }
        }

        bf16x8 a2[2];
        #pragma unroll
        for (int tt = 0; tt < 2; ++tt) {
            const int row = tt * 16 + l15;
            a2[tt] = *(const bf16x8*)&hs[wv][row][((lg ^ ((row >> 1) & 3))) * 8];
        }
        __builtin_amdgcn_s_setprio(1);
        #pragma unroll
        for (int ct = 0; ct < 16; ++ct) {
            const int br = ct * 16 + l15;
            const bf16x8 bW = *(const bf16x8*)&w2c[cur][br][((lg ^ ((br >> 1) & 3))) * 8];
            #pragma unroll
            for (int tt = 0; tt < 2; ++tt)
                acc2[tt][ct] = MFMA32(a2[tt], bW, acc2[tt][ct]);
        }
        __builtin_amdgcn_s_setprio(0);

        asm volatile("s_waitcnt vmcnt(0)" ::: "memory");
        __builtin_amdgcn_sched_barrier(0);
        __builtin_amdgcn_s_barrier();
        __builtin_amdgcn_sched_barrier(0);
    }

    #pragma unroll
    for (int tt = 0; tt < 2; ++tt) {
        #pragma unroll
        for (int q = 0; q < 4; ++q) {
            const int grow = tt * 16 + lg * 4 + q;
            const size_t tok = (size_t)(rowbase + grow);
            float s = 0.f, s2 = 0.f;
            float vals[16];
            #pragma unroll
            for (int ct = 0; ct < 16; ++ct) {
                const int col = ct * 16 + l15;
                const float v = acc2[tt][ct][q] + fc2b_s[col] + ALPHA * (float)x1b[tok * 256 + col];
                vals[ct] = v;
                s += v; s2 += v * v;
            }
            s  += __shfl_xor(s, 1, 16);  s += __shfl_xor(s, 2, 16);
            s  += __shfl_xor(s, 4, 16);  s += __shfl_xor(s, 8, 16);
            s2 += __shfl_xor(s2, 1, 16); s2 += __shfl_xor(s2, 2, 16);
            s2 += __shfl_xor(s2, 4, 16); s2 += __shfl_xor(s2, 8, 16);
            const float mu = s * (1.0f / 256.0f);
            const float var = s2 * (1.0f / 256.0f) - mu * mu;
            const float rstd = rsqrtf(var + 1e-5f);
            float* op = out + tok * 256;
            #pragma unroll
            for (int ct = 0; ct < 16; ++ct) {
                const int col = ct * 16 + l15;
                op[col] = (vals[ct] - mu) * rstd * n2w_s[col] + n2b_s[col];
            }
        }
    }
    #undef STAGE_W
}

// ---------------------------------------------------------------------------
extern "C" void kernel_launch(void* const* d_in, const int* in_sizes, int n_in,
                              void* d_out, int out_size, void* d_ws, size_t ws_size,
                              hipStream_t stream)
{
    const float* x          = (const float*)d_in[0];
    const float* qkv_w      = (const float*)d_in[1];
    const float* qkv_b      = (const float*)d_in[2];
    const float* bias_table = (const float*)d_in[3];
    const float* proj_w     = (const float*)d_in[4];
    const float* proj_b     = (const float*)d_in[5];
    const float* n1w        = (const float*)d_in[6];
    const float* n1b        = (const float*)d_in[7];
    const float* n2w        = (const float*)d_in[8];
    const float* n2b        = (const float*)d_in[9];
    const float* fc1_w      = (const float*)d_in[10];
    const float* fc1_b      = (const float*)d_in[11];
    const float* fc2_w      = (const float*)d_in[12];
    const float* fc2_b      = (const float*)d_in[13];
    float* out = (float*)d_out;

    // ws layout (bytes):
    //   [0,          75497472)  x1b bf16
    //   [75497472,  150994944)  attnout bf16
    //   [150994944, 152567808)  weight tables
    //   [152567808, 152862720)  bmask fp32 [4][8][48][48]
    char* ws = (char*)d_ws;
    __bf16* x1b     = (__bf16*)ws;
    __bf16* attnout = (__bf16*)(ws + 75497472);
    __bf16* qkvT    = (__bf16*)(ws + 150994944);
    __bf16* projT   = (__bf16*)(ws + 151388160);
    __bf16* w1T     = (__bf16*)(ws + 151519232);
    __bf16* w2T     = (__bf16*)(ws + 152043520);
    float*  bmask   = (float*)(ws + 152567808);

    k0_prep<<<3360, 256, 0, stream>>>(qkv_w, proj_w, fc1_w, fc2_w, bias_table,
                                      qkvT, projT, w1T, w2T, bmask);
    k1f_qkv_attn<<<4096, 512, 0, stream>>>(x, qkvT, qkv_b, bmask, attnout);
    k2_proj_ln<<<1152, 512, 0, stream>>>(attnout, projT, proj_b, x, n1w, n1b, x1b);
    k3f_mlp<<<1152, 256, 0, stream>>>(x1b, w1T, fc1_b, w2T, fc2_b, n2w, n2b, out);
}